// Round 18
// baseline (247.554 us; speedup 1.0000x reference)
//
#include <hip/hip_runtime.h>
#include <hip/hip_bf16.h>
#include <hip/hip_fp16.h>
#include <math.h>

constexpr int NN = 50000;
constexpr int EE = 800000;
constexpr int SCAN_NB = (NN + 255) / 256;   // 196
constexpr int HISTB   = (EE + 255) / 256;   // 3125
constexpr int GEMMB4  = (NN + 15) / 16;     // 3125 blocks: 4 waves = 1 tile x 4 col-quarters

typedef short v8s __attribute__((ext_vector_type(8)));
typedef float v4f __attribute__((ext_vector_type(4)));

__device__ __forceinline__ short f2b(float f){
  __hip_bfloat16 h = __float2bfloat16(f);
  return *reinterpret_cast<short*>(&h);
}
__device__ __forceinline__ __half2 u2h2(unsigned int u){
  union { unsigned int u; __half2 h; } c; c.u = u; return c.h;
}

// --- fused: hist-8copy (blocks [0,HISTB)) || pack (HISTB..+768) || Wb precombine ---
__global__ __launch_bounds__(256) void histpack_kernel(
    const int* __restrict__ ei, int* __restrict__ degC, int* __restrict__ epos,
    const float* __restrict__ Wq1, const float* __restrict__ bq1,
    const float* __restrict__ Wk1, const float* __restrict__ bk1,
    const float* __restrict__ Wv1, const float* __restrict__ bv1,
    const float* __restrict__ Ws1, const float* __restrict__ bs1,
    const float* __restrict__ Wq2, const float* __restrict__ bq2,
    const float* __restrict__ Wk2, const float* __restrict__ bk2,
    const float* __restrict__ Wv2, const float* __restrict__ bv2,
    const float* __restrict__ Ws2, const float* __restrict__ bs2,
    const float* __restrict__ Wb1, const float* __restrict__ Wb2,
    short* __restrict__ Wcat1, float* __restrict__ bcat1,
    short* __restrict__ Wcat2, float* __restrict__ bcat2,
    float* __restrict__ wa1, float* __restrict__ wc1,
    float* __restrict__ wa2, float* __restrict__ wc2){
  int b = blockIdx.x;
  if (b < HISTB){
    int e = b * 256 + threadIdx.x;
    if (e < EE){
      int dst = ei[EE + e];
      int c = b & 7;
      int old = atomicAdd(&degC[c * NN + dst], 1);
      epos[e] = (c << 28) | old;
    }
  } else if (b < HISTB + 768){
    int c = b - HISTB;
    int layer = c / 384, cc = c % 384;
    int which = cc / 96, r = cc % 96;
    const float *Wsel, *bsel;
    int K; short* Wd; float* bd;
    if (layer == 0){
      Wsel = which == 0 ? Wq1 : which == 1 ? Wk1 : which == 2 ? Wv1 : Ws1;
      bsel = which == 0 ? bq1 : which == 1 ? bk1 : which == 2 ? bv1 : bs1;
      K = 128; Wd = Wcat1; bd = bcat1;
    } else {
      Wsel = which == 0 ? Wq2 : which == 1 ? Wk2 : which == 2 ? Wv2 : Ws2;
      bsel = which == 0 ? bq2 : which == 1 ? bk2 : which == 2 ? bv2 : bs2;
      K = 96; Wd = Wcat2; bd = bcat2;
    }
    for (int k = threadIdx.x; k < K; k += blockDim.x)
      Wd[(size_t)cc * K + k] = f2b(Wsel[(size_t)r * K + k]);
    if (threadIdx.x == 0) bd[cc] = bsel[r];
  } else {
    int t = threadIdx.x;
    if (t < 96){
      wa1[t] = Wb1[t] + Wb1[192 + t];
      wc1[t] = Wb1[96 + t] - Wb1[192 + t];
    } else if (t < 192){
      int f = t - 96;
      wa2[f] = Wb2[f] + Wb2[192 + f];
      wc2[f] = Wb2[96 + f] - Wb2[192 + f];
    }
  }
}

// --- scan over summed 8-copy histogram ---
__global__ __launch_bounds__(256) void partial_sum_kernel(const int* __restrict__ degC,
                                                          int* __restrict__ psum){
  int b = blockIdx.x, tid = threadIdx.x, lane = tid & 63, wv = tid >> 6;
  int i = b * 256 + tid;
  int v = 0;
  if (i < NN){
    #pragma unroll
    for (int c = 0; c < 8; c++) v += degC[c * NN + i];
  }
  #pragma unroll
  for (int m = 1; m < 64; m <<= 1) v += __shfl_xor(v, m);
  __shared__ int ws[4];
  if (lane == 0) ws[wv] = v;
  __syncthreads();
  if (tid == 0) psum[b] = ws[0] + ws[1] + ws[2] + ws[3];
}

__global__ __launch_bounds__(256) void scan_partials_kernel(int* __restrict__ psum){
  int tid = threadIdx.x, lane = tid & 63, wv = tid >> 6;
  int own = (tid < SCAN_NB) ? psum[tid] : 0;
  int v = own;
  #pragma unroll
  for (int off = 1; off < 64; off <<= 1){
    int t = __shfl_up(v, off);
    if (lane >= off) v += t;
  }
  __shared__ int ws[4];
  if (lane == 63) ws[wv] = v;
  __syncthreads();
  int add = 0;
  #pragma unroll
  for (int w = 0; w < 4; w++) if (w < wv) add += ws[w];
  if (tid < SCAN_NB) psum[tid] = v + add - own;     // exclusive
}

__global__ __launch_bounds__(256) void final_scan_kernel(const int* __restrict__ degC,
                                                         const int* __restrict__ psum,
                                                         int* __restrict__ row_ptr,
                                                         int* __restrict__ base8){
  int b = blockIdx.x, tid = threadIdx.x, lane = tid & 63, wv = tid >> 6;
  int i = b * 256 + tid;
  int dc[8];
  int d = 0;
  if (i < NN){
    #pragma unroll
    for (int c = 0; c < 8; c++){ dc[c] = degC[c * NN + i]; d += dc[c]; }
  } else {
    #pragma unroll
    for (int c = 0; c < 8; c++) dc[c] = 0;
  }
  int v = d;
  #pragma unroll
  for (int off = 1; off < 64; off <<= 1){
    int t = __shfl_up(v, off);
    if (lane >= off) v += t;
  }
  __shared__ int ws[4];
  if (lane == 63) ws[wv] = v;
  __syncthreads();
  int add = psum[b];
  #pragma unroll
  for (int w = 0; w < 4; w++) if (w < wv) add += ws[w];
  if (i < NN){
    int start = add + v - d;
    row_ptr[i + 1] = add + v;
    int run = start;
    #pragma unroll
    for (int c = 0; c < 8; c++){
      base8[(size_t)i * 8 + c] = run;
      run += dc[c];
    }
  }
  if (i == 0) row_ptr[0] = 0;
}

__global__ void fill_kernel(const int* __restrict__ ei, const int* __restrict__ epos,
                            const int* __restrict__ base8,
                            unsigned short* __restrict__ col_src){
  int e = blockIdx.x * blockDim.x + threadIdx.x;
  if (e < EE){
    int src = ei[e], dst = ei[EE + e];
    unsigned int u = (unsigned int)epos[e];
    int c = u >> 28, cnt = u & 0x0FFFFFFF;
    int pos = base8[(size_t)dst * 8 + c] + cnt;
    col_src[pos] = (unsigned short)src;
  }
}

// GEMM: 4-way column split per 16-row tile (12500 waves). ALL B/A loads issued,
// then ONE asm volatile consumes every loaded value ("+v") -> values are opaque
// asm outputs (cannot be rematerialized/sunk by regalloc) and all ~24 independent
// 16B loads must be in flight before a single waitcnt. True MLP test.
template<int K, bool AF32>
__global__ __launch_bounds__(256) void gemm_kernel(const void* __restrict__ Ain,
                                                   const short* __restrict__ Wcat,
                                                   const float* __restrict__ bcat,
                                                   __half* __restrict__ qsh,
                                                   __half* __restrict__ kvb, int M){
  constexpr int NK = K / 32;             // 4 (K=128) / 3 (K=96)
  const int tid = threadIdx.x;
  const int lane = tid & 63;
  const int wave_id = blockIdx.x * 4 + (tid >> 6);
  const int tile = wave_id >> 2;
  const int quarter = wave_id & 3;
  if (tile * 16 >= M) return;
  const int rt = tile * 16;
  const int fr = lane & 15, fk = lane >> 4;
  const int arow = rt + fr;              // < M (M % 16 == 0)

  // issue ALL B loads (24/18 independent 16B loads)
  v8s bb[6][NK];
  #pragma unroll
  for (int pp = 0; pp < 6; pp++){
    const int gcol = (quarter * 6 + pp) * 16 + fr;
    #pragma unroll
    for (int ks = 0; ks < NK; ks++)
      bb[pp][ks] = *(const v8s*)(Wcat + (size_t)gcol * K + ks * 32 + fk * 8);
  }

  v8s a[NK];
  if constexpr (AF32){
    const float* A = (const float*)Ain;
    #pragma unroll
    for (int ks = 0; ks < NK; ks++){
      const float* p = A + (size_t)arow * K + ks * 32 + fk * 8;
      float4 a0 = *(const float4*)p;
      float4 a1 = *(const float4*)(p + 4);
      v8s o;
      o[0] = f2b(a0.x); o[1] = f2b(a0.y); o[2] = f2b(a0.z); o[3] = f2b(a0.w);
      o[4] = f2b(a1.x); o[5] = f2b(a1.y); o[6] = f2b(a1.z); o[7] = f2b(a1.w);
      a[ks] = o;
    }
  } else {
    const short* A = (const short*)Ain;
    #pragma unroll
    for (int ks = 0; ks < NK; ks++)
      a[ks] = *(const v8s*)(A + (size_t)arow * K + ks * 32 + fk * 8);
  }

  // single opaque pin: all loaded values become asm outputs (no remat, one waitcnt)
  if constexpr (NK == 4){
    asm volatile("" :
      "+v"(bb[0][0]), "+v"(bb[0][1]), "+v"(bb[0][2]), "+v"(bb[0][3]),
      "+v"(bb[1][0]), "+v"(bb[1][1]), "+v"(bb[1][2]), "+v"(bb[1][3]),
      "+v"(bb[2][0]), "+v"(bb[2][1]), "+v"(bb[2][2]), "+v"(bb[2][3]),
      "+v"(bb[3][0]), "+v"(bb[3][1]), "+v"(bb[3][2]), "+v"(bb[3][3]),
      "+v"(bb[4][0]), "+v"(bb[4][1]), "+v"(bb[4][2]), "+v"(bb[4][3]),
      "+v"(bb[5][0]), "+v"(bb[5][1]), "+v"(bb[5][2]), "+v"(bb[5][3]),
      "+v"(a[0]), "+v"(a[1]), "+v"(a[2]), "+v"(a[3]));
  } else {
    asm volatile("" :
      "+v"(bb[0][0]), "+v"(bb[0][1]), "+v"(bb[0][2]),
      "+v"(bb[1][0]), "+v"(bb[1][1]), "+v"(bb[1][2]),
      "+v"(bb[2][0]), "+v"(bb[2][1]), "+v"(bb[2][2]),
      "+v"(bb[3][0]), "+v"(bb[3][1]), "+v"(bb[3][2]),
      "+v"(bb[4][0]), "+v"(bb[4][1]), "+v"(bb[4][2]),
      "+v"(bb[5][0]), "+v"(bb[5][1]), "+v"(bb[5][2]),
      "+v"(a[0]), "+v"(a[1]), "+v"(a[2]));
  }

  #pragma unroll
  for (int pp = 0; pp < 6; pp++){
    const int p = quarter * 6 + pp;
    const int c0 = p * 16;
    const int gcol = c0 + fr;
    v4f acc = (v4f){0.f, 0.f, 0.f, 0.f};
    #pragma unroll
    for (int ks = 0; ks < NK; ks++)
      acc = __builtin_amdgcn_mfma_f32_16x16x32_bf16(a[ks], bb[pp][ks], acc, 0, 0, 0);
    const float bias = bcat[gcol];
    if (c0 < 96){
      #pragma unroll
      for (int r = 0; r < 4; r++)
        qsh[(size_t)(rt + fk * 4 + r) * 192 + gcol] = __float2half(acc[r] + bias);
    } else if (c0 < 192){
      #pragma unroll
      for (int r = 0; r < 4; r++)
        kvb[(size_t)(rt + fk * 4 + r) * 192 + (gcol - 96)] = __float2half(acc[r] + bias);
    } else if (c0 < 288){
      #pragma unroll
      for (int r = 0; r < 4; r++)
        kvb[(size_t)(rt + fk * 4 + r) * 192 + 96 + (gcol - 192)] = __float2half(acc[r] + bias);
    } else {
      #pragma unroll
      for (int r = 0; r < 4; r++)
        qsh[(size_t)(rt + fk * 4 + r) * 192 + 96 + (gcol - 288)] = __float2half(acc[r] + bias);
    }
  }
}

// one wave per node; chunk of 16 edges. qs (q+skip) and kv rows f16. (round-12, proven)
__global__ __launch_bounds__(256) void attn_kernel(
    const __half* __restrict__ qs, const __half* __restrict__ kv,
    const int* __restrict__ row_ptr, const unsigned short* __restrict__ col_src,
    const float* __restrict__ wa, const float* __restrict__ wc,
    const float* __restrict__ gamma, const float* __restrict__ beta,
    float* __restrict__ outp, short* __restrict__ h1b, int mode){
  const int lane = threadIdx.x & 63;
  const int wid  = threadIdx.x >> 6;
  const int n = blockIdx.x * 4 + wid;
  if (n >= NN) return;
  const int h_a = lane & 3;
  const int g_a = lane >> 2;
  const int l_v = lane & 15;
  const int vg  = lane >> 4;
  const int h_v = l_v >> 2;
  const char* kvc = (const char*)kv;
  const char* qsc = (const char*)qs;

  __half2 qh[12];
  {
    const uint4* qp = (const uint4*)(qsc + (size_t)n * 384 + h_a * 48);
    uint4 a0 = qp[0], a1 = qp[1], a2 = qp[2];
    qh[0] = u2h2(a0.x); qh[1] = u2h2(a0.y); qh[2]  = u2h2(a0.z); qh[3]  = u2h2(a0.w);
    qh[4] = u2h2(a1.x); qh[5] = u2h2(a1.y); qh[6]  = u2h2(a1.z); qh[7]  = u2h2(a1.w);
    qh[8] = u2h2(a2.x); qh[9] = u2h2(a2.y); qh[10] = u2h2(a2.z); qh[11] = u2h2(a2.w);
  }
  const int rs = row_ptr[n], re = row_ptr[n + 1];
  float m = -INFINITY, s = 0.f;
  float acc[6] = {0.f, 0.f, 0.f, 0.f, 0.f, 0.f};

  for (int cb = rs; cb < re; cb += 16){
    const int cn = re - cb;             // >=1
    int srcv = col_src[cb + min(g_a, cn - 1)];
    int sb[4];
    #pragma unroll
    for (int st = 0; st < 4; st++)
      sb[st] = __shfl(srcv, 4 * min(st * 4 + vg, cn - 1));
    unsigned int vd[4][3];
    #pragma unroll
    for (int st = 0; st < 4; st++){
      const unsigned int* vp =
        (const unsigned int*)(kvc + (size_t)sb[st] * 384 + 192 + 12 * l_v);
      vd[st][0] = vp[0]; vd[st][1] = vp[1]; vd[st][2] = vp[2];
    }
    const uint4* kp = (const uint4*)(kvc + (size_t)srcv * 384 + h_a * 48);
    uint4 u0 = kp[0], u1 = kp[1], u2 = kp[2];
    __half2 d0 = __floats2half2_rn(0.f, 0.f), d1 = d0;
    d0 = __hfma2(qh[0],  u2h2(u0.x), d0); d1 = __hfma2(qh[1],  u2h2(u0.y), d1);
    d0 = __hfma2(qh[2],  u2h2(u0.z), d0); d1 = __hfma2(qh[3],  u2h2(u0.w), d1);
    d0 = __hfma2(qh[4],  u2h2(u1.x), d0); d1 = __hfma2(qh[5],  u2h2(u1.y), d1);
    d0 = __hfma2(qh[6],  u2h2(u1.z), d0); d1 = __hfma2(qh[7],  u2h2(u1.w), d1);
    d0 = __hfma2(qh[8],  u2h2(u2.x), d0); d1 = __hfma2(qh[9],  u2h2(u2.y), d1);
    d0 = __hfma2(qh[10], u2h2(u2.z), d0); d1 = __hfma2(qh[11], u2h2(u2.w), d1);
    float dot = __low2float(d0) + __high2float(d0) + __low2float(d1) + __high2float(d1);
    float al = (g_a < cn) ? dot * 0.2041241452319315f : -INFINITY;

    float cm = al;
    cm = fmaxf(cm, __shfl_xor(cm, 4));
    cm = fmaxf(cm, __shfl_xor(cm, 8));
    cm = fmaxf(cm, __shfl_xor(cm, 16));
    cm = fmaxf(cm, __shfl_xor(cm, 32));
    float nm = fmaxf(m, cm);
    float r  = __expf(m - nm);          // first chunk: 0
    float e  = __expf(al - nm);         // padded lanes: 0
    float cs = e;
    cs += __shfl_xor(cs, 4);
    cs += __shfl_xor(cs, 8);
    cs += __shfl_xor(cs, 16);
    cs += __shfl_xor(cs, 32);
    s = s * r + cs;
    m = nm;

    float rv = __shfl(r, h_v);
    __half2 ch0 = __floats2half2_rn(0.f, 0.f), ch1 = ch0, ch2 = ch0;
    #pragma unroll
    for (int st = 0; st < 4; st++){
      int eidx = st * 4 + vg;
      float w = __shfl(e, 4 * min(eidx, cn - 1) + h_v);
      if (eidx >= cn) w = 0.f;
      __half2 w2 = __float2half2_rn(w);
      ch0 = __hfma2(w2, u2h2(vd[st][0]), ch0);
      ch1 = __hfma2(w2, u2h2(vd[st][1]), ch1);
      ch2 = __hfma2(w2, u2h2(vd[st][2]), ch2);
    }
    acc[0] = fmaf(acc[0], rv, __low2float(ch0));
    acc[1] = fmaf(acc[1], rv, __high2float(ch0));
    acc[2] = fmaf(acc[2], rv, __low2float(ch1));
    acc[3] = fmaf(acc[3], rv, __high2float(ch1));
    acc[4] = fmaf(acc[4], rv, __low2float(ch2));
    acc[5] = fmaf(acc[5], rv, __high2float(ch2));
  }

  #pragma unroll
  for (int i = 0; i < 6; i++){
    acc[i] += __shfl_xor(acc[i], 16);
    acc[i] += __shfl_xor(acc[i], 32);
  }
  float sv  = __shfl(s, h_v);
  float inv = (re > rs) ? 1.0f / sv : 0.f;
  float o[6], xr[6];
  #pragma unroll
  for (int i = 0; i < 6; i++) o[i] = acc[i] * inv;
  {
    const unsigned int* xp = (const unsigned int*)(qsc + (size_t)n * 384 + 192 + 12 * l_v);
    unsigned int x0 = xp[0], x1 = xp[1], x2 = xp[2];
    xr[0] = __low2float(u2h2(x0)); xr[1] = __high2float(u2h2(x0));
    xr[2] = __low2float(u2h2(x1)); xr[3] = __high2float(u2h2(x1));
    xr[4] = __low2float(u2h2(x2)); xr[5] = __high2float(u2h2(x2));
  }

  float p = 0.f;
  #pragma unroll
  for (int i = 0; i < 6; i++){
    int f = 6 * l_v + i;
    p = fmaf(o[i], wa[f], p);
    p = fmaf(xr[i], wc[f], p);
  }
  p += __shfl_xor(p, 1);
  p += __shfl_xor(p, 2);
  p += __shfl_xor(p, 4);
  p += __shfl_xor(p, 8);
  float g = 1.0f / (1.0f + __expf(-p));
  float y[6];
  #pragma unroll
  for (int i = 0; i < 6; i++) y[i] = fmaf(g, xr[i] - o[i], o[i]);

  if (mode == 0){
    #pragma unroll
    for (int i = 0; i < 6; i++)
      y[i] = 0.5f * y[i] * (1.0f + erff(y[i] * 0.7071067811865475f));
    if (vg == 0){
      short* op = h1b + (size_t)n * 96 + 6 * l_v;
      #pragma unroll
      for (int i = 0; i < 6; i++) op[i] = f2b(y[i]);
    }
  } else {
    float ssum = y[0] + y[1] + y[2] + y[3] + y[4] + y[5];
    ssum += __shfl_xor(ssum, 1);
    ssum += __shfl_xor(ssum, 2);
    ssum += __shfl_xor(ssum, 4);
    ssum += __shfl_xor(ssum, 8);
    float mu = ssum * (1.0f / 96.0f);
    float vsum = 0.f;
    #pragma unroll
    for (int i = 0; i < 6; i++){ float d = y[i] - mu; vsum += d * d; }
    vsum += __shfl_xor(vsum, 1);
    vsum += __shfl_xor(vsum, 2);
    vsum += __shfl_xor(vsum, 4);
    vsum += __shfl_xor(vsum, 8);
    float invs = rsqrtf(vsum * (1.0f / 96.0f) + 1e-5f);
    if (vg == 0){
      float* op = outp + (size_t)n * 96 + 6 * l_v;
      #pragma unroll
      for (int i = 0; i < 6; i++){
        int f = 6 * l_v + i;
        op[i] = (y[i] - mu) * invs * gamma[f] + beta[f];
      }
    }
  }
}

extern "C" void kernel_launch(void* const* d_in, const int* in_sizes, int n_in,
                              void* d_out, int out_size, void* d_ws, size_t ws_size,
                              hipStream_t stream){
  const float* x    = (const float*)d_in[0];
  const int*   ei   = (const int*)d_in[1];
  const float* Wq1  = (const float*)d_in[2];
  const float* bq1  = (const float*)d_in[3];
  const float* Wk1  = (const float*)d_in[4];
  const float* bk1  = (const float*)d_in[5];
  const float* Wv1  = (const float*)d_in[6];
  const float* bv1  = (const float*)d_in[7];
  const float* Ws1  = (const float*)d_in[8];
  const float* bs1  = (const float*)d_in[9];
  const float* Wb1  = (const float*)d_in[10];
  const float* Wq2  = (const float*)d_in[11];
  const float* bq2  = (const float*)d_in[12];
  const float* Wk2  = (const float*)d_in[13];
  const float* bk2  = (const float*)d_in[14];
  const float* Wv2  = (const float*)d_in[15];
  const float* bv2  = (const float*)d_in[16];
  const float* Ws2  = (const float*)d_in[17];
  const float* bs2  = (const float*)d_in[18];
  const float* Wb2  = (const float*)d_in[19];
  const float* gamma = (const float*)d_in[20];
  const float* beta  = (const float*)d_in[21];
  float* out = (float*)d_out;

  char* ws = (char*)d_ws;
  size_t off = 0;
  auto take = [&](size_t b) -> void* {
    void* p = ws + off;
    off += (b + 255) & ~(size_t)255;
    return p;
  };
  __half* qs           = (__half*)take((size_t)NN * 192 * 2);
  __half* kvb          = (__half*)take((size_t)NN * 192 * 2);
  short* h1b           = (short*)take((size_t)NN * 96 * 2);
  short* Wcat1         = (short*)take((size_t)384 * 128 * 2);
  short* Wcat2         = (short*)take((size_t)384 * 96 * 2);
  float* bcat1         = (float*)take(384 * 4);
  float* bcat2         = (float*)take(384 * 4);
  float* wa1           = (float*)take(96 * 4);
  float* wc1           = (float*)take(96 * 4);
  float* wa2           = (float*)take(96 * 4);
  float* wc2           = (float*)take(96 * 4);
  int* degC            = (int*)take((size_t)8 * NN * 4);
  int* epos            = (int*)take((size_t)EE * 4);
  int* base8           = (int*)take((size_t)NN * 8 * 4);
  int* row_ptr         = (int*)take((size_t)(NN + 1) * 4);
  unsigned short* col_src = (unsigned short*)take((size_t)EE * 2);
  int* psum            = (int*)take((size_t)SCAN_NB * 4);

  hipMemsetAsync(degC, 0, (size_t)8 * NN * 4, stream);
  histpack_kernel<<<HISTB + 768 + 1, 256, 0, stream>>>(
      ei, degC, epos,
      Wq1, bq1, Wk1, bk1, Wv1, bv1, Ws1, bs1,
      Wq2, bq2, Wk2, bk2, Wv2, bv2, Ws2, bs2,
      Wb1, Wb2, Wcat1, bcat1, Wcat2, bcat2, wa1, wc1, wa2, wc2);
  partial_sum_kernel<<<SCAN_NB, 256, 0, stream>>>(degC, psum);
  scan_partials_kernel<<<1, 256, 0, stream>>>(psum);
  final_scan_kernel<<<SCAN_NB, 256, 0, stream>>>(degC, psum, row_ptr, base8);
  fill_kernel<<<(EE + 255) / 256, 256, 0, stream>>>(ei, epos, base8, col_src);

  // layer 1
  gemm_kernel<128, true><<<GEMMB4, 256, 0, stream>>>(x, Wcat1, bcat1, qs, kvb, NN);
  attn_kernel<<<(NN + 3) / 4, 256, 0, stream>>>(qs, kvb, row_ptr, col_src,
                                                wa1, wc1, nullptr, nullptr,
                                                nullptr, h1b, 0);
  // layer 2
  gemm_kernel<96, false><<<GEMMB4, 256, 0, stream>>>(h1b, Wcat2, bcat2, qs, kvb, NN);
  attn_kernel<<<(NN + 3) / 4, 256, 0, stream>>>(qs, kvb, row_ptr, col_src,
                                                wa2, wc2, gamma, beta,
                                                out, nullptr, 1);
}

// Round 19
// 240.719 us; speedup vs baseline: 1.0284x; 1.0284x over previous
//
#include <hip/hip_runtime.h>
#include <hip/hip_bf16.h>
#include <hip/hip_fp16.h>
#include <math.h>

constexpr int NN = 50000;
constexpr int EE = 800000;
constexpr int SCAN_NB = (NN + 255) / 256;   // 196
constexpr int HISTB   = (EE + 255) / 256;   // 3125
constexpr int GEMMB4  = (NN + 15) / 16;     // 3125 (4 waves = 1 tile x 4 col-quarters)

typedef short v8s __attribute__((ext_vector_type(8)));
typedef float v4f __attribute__((ext_vector_type(4)));

__device__ __forceinline__ short f2b(float f){
  __hip_bfloat16 h = __float2bfloat16(f);
  return *reinterpret_cast<short*>(&h);
}
__device__ __forceinline__ __half2 u2h2(unsigned int u){
  union { unsigned int u; __half2 h; } c; c.u = u; return c.h;
}

// --- pack both layers' weights + Wb precombine (769 blocks) ---
__global__ __launch_bounds__(128) void pack_kernel(
    const float* __restrict__ Wq1, const float* __restrict__ bq1,
    const float* __restrict__ Wk1, const float* __restrict__ bk1,
    const float* __restrict__ Wv1, const float* __restrict__ bv1,
    const float* __restrict__ Ws1, const float* __restrict__ bs1,
    const float* __restrict__ Wq2, const float* __restrict__ bq2,
    const float* __restrict__ Wk2, const float* __restrict__ bk2,
    const float* __restrict__ Wv2, const float* __restrict__ bv2,
    const float* __restrict__ Ws2, const float* __restrict__ bs2,
    const float* __restrict__ Wb1, const float* __restrict__ Wb2,
    short* __restrict__ Wcat1, float* __restrict__ bcat1,
    short* __restrict__ Wcat2, float* __restrict__ bcat2,
    float* __restrict__ wa1, float* __restrict__ wc1,
    float* __restrict__ wa2, float* __restrict__ wc2){
  int c = blockIdx.x;
  if (c < 768){
    int layer = c / 384, cc = c % 384;
    int which = cc / 96, r = cc % 96;
    const float *Wsel, *bsel;
    int K; short* Wd; float* bd;
    if (layer == 0){
      Wsel = which == 0 ? Wq1 : which == 1 ? Wk1 : which == 2 ? Wv1 : Ws1;
      bsel = which == 0 ? bq1 : which == 1 ? bk1 : which == 2 ? bv1 : bs1;
      K = 128; Wd = Wcat1; bd = bcat1;
    } else {
      Wsel = which == 0 ? Wq2 : which == 1 ? Wk2 : which == 2 ? Wv2 : Ws2;
      bsel = which == 0 ? bq2 : which == 1 ? bk2 : which == 2 ? bv2 : bs2;
      K = 96; Wd = Wcat2; bd = bcat2;
    }
    for (int k = threadIdx.x; k < K; k += blockDim.x)
      Wd[(size_t)cc * K + k] = f2b(Wsel[(size_t)r * K + k]);
    if (threadIdx.x == 0) bd[cc] = bsel[r];
  } else {
    int t = threadIdx.x;
    if (t < 96){
      wa1[t] = Wb1[t] + Wb1[192 + t];
      wc1[t] = Wb1[96 + t] - Wb1[192 + t];
      wa2[t] = Wb2[t] + Wb2[192 + t];
      wc2[t] = Wb2[96 + t] - Wb2[192 + t];
    }
  }
}

// gemm per-wave body (round-15 form, best measured: VGPR 32, 56.6us):
// wave = (tile, quarter); quarter handles 6 of 24 16-col B-strips; A reg-resident.
template<int K, bool AF32>
__device__ __forceinline__ void gemm_body(int wave_id, const void* __restrict__ Ain,
                                          const short* __restrict__ Wcat,
                                          const float* __restrict__ bcat,
                                          __half* __restrict__ qsh,
                                          __half* __restrict__ kvb, int M){
  constexpr int NK = K / 32;             // 4 (K=128) / 3 (K=96)
  const int lane = threadIdx.x & 63;
  const int tile = wave_id >> 2;
  const int quarter = wave_id & 3;
  if (tile * 16 >= M) return;
  const int rt = tile * 16;
  const int fr = lane & 15, fk = lane >> 4;
  const int arow = rt + fr;              // < M (M % 16 == 0)

  v8s a[NK];
  if constexpr (AF32){
    const float* A = (const float*)Ain;
    #pragma unroll
    for (int ks = 0; ks < NK; ks++){
      const float* p = A + (size_t)arow * K + ks * 32 + fk * 8;
      float4 a0 = *(const float4*)p;
      float4 a1 = *(const float4*)(p + 4);
      v8s o;
      o[0] = f2b(a0.x); o[1] = f2b(a0.y); o[2] = f2b(a0.z); o[3] = f2b(a0.w);
      o[4] = f2b(a1.x); o[5] = f2b(a1.y); o[6] = f2b(a1.z); o[7] = f2b(a1.w);
      a[ks] = o;
    }
  } else {
    const short* A = (const short*)Ain;
    #pragma unroll
    for (int ks = 0; ks < NK; ks++)
      a[ks] = *(const v8s*)(A + (size_t)arow * K + ks * 32 + fk * 8);
  }

  #pragma unroll
  for (int pp = 0; pp < 6; pp++){
    const int p = quarter * 6 + pp;
    const int c0 = p * 16;
    const int gcol = c0 + fr;
    v4f acc = (v4f){0.f, 0.f, 0.f, 0.f};
    #pragma unroll
    for (int ks = 0; ks < NK; ks++){
      v8s b = *(const v8s*)(Wcat + (size_t)gcol * K + ks * 32 + fk * 8);
      acc = __builtin_amdgcn_mfma_f32_16x16x32_bf16(a[ks], b, acc, 0, 0, 0);
    }
    const float bias = bcat[gcol];
    if (c0 < 96){
      #pragma unroll
      for (int r = 0; r < 4; r++)
        qsh[(size_t)(rt + fk * 4 + r) * 192 + gcol] = __float2half(acc[r] + bias);
    } else if (c0 < 192){
      #pragma unroll
      for (int r = 0; r < 4; r++)
        kvb[(size_t)(rt + fk * 4 + r) * 192 + (gcol - 96)] = __float2half(acc[r] + bias);
    } else if (c0 < 288){
      #pragma unroll
      for (int r = 0; r < 4; r++)
        kvb[(size_t)(rt + fk * 4 + r) * 192 + 96 + (gcol - 192)] = __float2half(acc[r] + bias);
    } else {
      #pragma unroll
      for (int r = 0; r < 4; r++)
        qsh[(size_t)(rt + fk * 4 + r) * 192 + 96 + (gcol - 288)] = __float2half(acc[r] + bias);
    }
  }
}

// --- fused: hist-8copy (blocks [0,HISTB)) || layer-1 gemm (blocks [HISTB,HISTB+GEMMB4)) ---
// hist: copy c = b&7 (XCD round-robin heuristic); epos[e]=(c<<28)|old -> atomic-free fill.
// hist traffic is tiny (1.6MB XCD-local atomics + 3.2MB coalesced epos) -> minimal
// cache antagonism with the gemm (unlike the failed fill||gemm fusion).
__global__ __launch_bounds__(256) void histgemm_kernel(
    const int* __restrict__ ei, int* __restrict__ degC, int* __restrict__ epos,
    const void* __restrict__ Ain, const short* __restrict__ Wcat,
    const float* __restrict__ bcat, __half* __restrict__ qsh,
    __half* __restrict__ kvb, int M){
  int b = blockIdx.x;
  if (b < HISTB){
    int e = b * 256 + threadIdx.x;
    if (e < EE){
      int dst = ei[EE + e];
      int c = b & 7;
      int old = atomicAdd(&degC[c * NN + dst], 1);
      epos[e] = (c << 28) | old;
    }
  } else {
    int wave_id = (b - HISTB) * 4 + (threadIdx.x >> 6);
    gemm_body<128, true>(wave_id, Ain, Wcat, bcat, qsh, kvb, M);
  }
}

// standalone gemm (layer 2)
template<int K, bool AF32>
__global__ __launch_bounds__(256) void gemm_kernel(const void* __restrict__ Ain,
                                                   const short* __restrict__ Wcat,
                                                   const float* __restrict__ bcat,
                                                   __half* __restrict__ qsh,
                                                   __half* __restrict__ kvb, int M){
  int wave_id = blockIdx.x * 4 + (threadIdx.x >> 6);
  gemm_body<K, AF32>(wave_id, Ain, Wcat, bcat, qsh, kvb, M);
}

// --- scan over summed 8-copy histogram ---
__global__ __launch_bounds__(256) void partial_sum_kernel(const int* __restrict__ degC,
                                                          int* __restrict__ psum){
  int b = blockIdx.x, tid = threadIdx.x, lane = tid & 63, wv = tid >> 6;
  int i = b * 256 + tid;
  int v = 0;
  if (i < NN){
    #pragma unroll
    for (int c = 0; c < 8; c++) v += degC[c * NN + i];
  }
  #pragma unroll
  for (int m = 1; m < 64; m <<= 1) v += __shfl_xor(v, m);
  __shared__ int ws[4];
  if (lane == 0) ws[wv] = v;
  __syncthreads();
  if (tid == 0) psum[b] = ws[0] + ws[1] + ws[2] + ws[3];
}

__global__ __launch_bounds__(256) void scan_partials_kernel(int* __restrict__ psum){
  int tid = threadIdx.x, lane = tid & 63, wv = tid >> 6;
  int own = (tid < SCAN_NB) ? psum[tid] : 0;
  int v = own;
  #pragma unroll
  for (int off = 1; off < 64; off <<= 1){
    int t = __shfl_up(v, off);
    if (lane >= off) v += t;
  }
  __shared__ int ws[4];
  if (lane == 63) ws[wv] = v;
  __syncthreads();
  int add = 0;
  #pragma unroll
  for (int w = 0; w < 4; w++) if (w < wv) add += ws[w];
  if (tid < SCAN_NB) psum[tid] = v + add - own;     // exclusive
}

__global__ __launch_bounds__(256) void final_scan_kernel(const int* __restrict__ degC,
                                                         const int* __restrict__ psum,
                                                         int* __restrict__ row_ptr,
                                                         int* __restrict__ base8){
  int b = blockIdx.x, tid = threadIdx.x, lane = tid & 63, wv = tid >> 6;
  int i = b * 256 + tid;
  int dc[8];
  int d = 0;
  if (i < NN){
    #pragma unroll
    for (int c = 0; c < 8; c++){ dc[c] = degC[c * NN + i]; d += dc[c]; }
  } else {
    #pragma unroll
    for (int c = 0; c < 8; c++) dc[c] = 0;
  }
  int v = d;
  #pragma unroll
  for (int off = 1; off < 64; off <<= 1){
    int t = __shfl_up(v, off);
    if (lane >= off) v += t;
  }
  __shared__ int ws[4];
  if (lane == 63) ws[wv] = v;
  __syncthreads();
  int add = psum[b];
  #pragma unroll
  for (int w = 0; w < 4; w++) if (w < wv) add += ws[w];
  if (i < NN){
    int start = add + v - d;
    row_ptr[i + 1] = add + v;
    int run = start;
    #pragma unroll
    for (int c = 0; c < 8; c++){
      base8[(size_t)i * 8 + c] = run;
      run += dc[c];
    }
  }
  if (i == 0) row_ptr[0] = 0;
}

__global__ void fill_kernel(const int* __restrict__ ei, const int* __restrict__ epos,
                            const int* __restrict__ base8,
                            unsigned short* __restrict__ col_src){
  int e = blockIdx.x * blockDim.x + threadIdx.x;
  if (e < EE){
    int src = ei[e], dst = ei[EE + e];
    unsigned int u = (unsigned int)epos[e];
    int c = u >> 28, cnt = u & 0x0FFFFFFF;
    int pos = base8[(size_t)dst * 8 + c] + cnt;
    col_src[pos] = (unsigned short)src;
  }
}

// one wave per node; chunk of 16 edges. qs (q+skip) and kv rows f16. (round-12, proven)
__global__ __launch_bounds__(256) void attn_kernel(
    const __half* __restrict__ qs, const __half* __restrict__ kv,
    const int* __restrict__ row_ptr, const unsigned short* __restrict__ col_src,
    const float* __restrict__ wa, const float* __restrict__ wc,
    const float* __restrict__ gamma, const float* __restrict__ beta,
    float* __restrict__ outp, short* __restrict__ h1b, int mode){
  const int lane = threadIdx.x & 63;
  const int wid  = threadIdx.x >> 6;
  const int n = blockIdx.x * 4 + wid;
  if (n >= NN) return;
  const int h_a = lane & 3;
  const int g_a = lane >> 2;
  const int l_v = lane & 15;
  const int vg  = lane >> 4;
  const int h_v = l_v >> 2;
  const char* kvc = (const char*)kv;
  const char* qsc = (const char*)qs;

  __half2 qh[12];
  {
    const uint4* qp = (const uint4*)(qsc + (size_t)n * 384 + h_a * 48);
    uint4 a0 = qp[0], a1 = qp[1], a2 = qp[2];
    qh[0] = u2h2(a0.x); qh[1] = u2h2(a0.y); qh[2]  = u2h2(a0.z); qh[3]  = u2h2(a0.w);
    qh[4] = u2h2(a1.x); qh[5] = u2h2(a1.y); qh[6]  = u2h2(a1.z); qh[7]  = u2h2(a1.w);
    qh[8] = u2h2(a2.x); qh[9] = u2h2(a2.y); qh[10] = u2h2(a2.z); qh[11] = u2h2(a2.w);
  }
  const int rs = row_ptr[n], re = row_ptr[n + 1];
  float m = -INFINITY, s = 0.f;
  float acc[6] = {0.f, 0.f, 0.f, 0.f, 0.f, 0.f};

  for (int cb = rs; cb < re; cb += 16){
    const int cn = re - cb;             // >=1
    int srcv = col_src[cb + min(g_a, cn - 1)];
    int sb[4];
    #pragma unroll
    for (int st = 0; st < 4; st++)
      sb[st] = __shfl(srcv, 4 * min(st * 4 + vg, cn - 1));
    unsigned int vd[4][3];
    #pragma unroll
    for (int st = 0; st < 4; st++){
      const unsigned int* vp =
        (const unsigned int*)(kvc + (size_t)sb[st] * 384 + 192 + 12 * l_v);
      vd[st][0] = vp[0]; vd[st][1] = vp[1]; vd[st][2] = vp[2];
    }
    const uint4* kp = (const uint4*)(kvc + (size_t)srcv * 384 + h_a * 48);
    uint4 u0 = kp[0], u1 = kp[1], u2 = kp[2];
    __half2 d0 = __floats2half2_rn(0.f, 0.f), d1 = d0;
    d0 = __hfma2(qh[0],  u2h2(u0.x), d0); d1 = __hfma2(qh[1],  u2h2(u0.y), d1);
    d0 = __hfma2(qh[2],  u2h2(u0.z), d0); d1 = __hfma2(qh[3],  u2h2(u0.w), d1);
    d0 = __hfma2(qh[4],  u2h2(u1.x), d0); d1 = __hfma2(qh[5],  u2h2(u1.y), d1);
    d0 = __hfma2(qh[6],  u2h2(u1.z), d0); d1 = __hfma2(qh[7],  u2h2(u1.w), d1);
    d0 = __hfma2(qh[8],  u2h2(u2.x), d0); d1 = __hfma2(qh[9],  u2h2(u2.y), d1);
    d0 = __hfma2(qh[10], u2h2(u2.z), d0); d1 = __hfma2(qh[11], u2h2(u2.w), d1);
    float dot = __low2float(d0) + __high2float(d0) + __low2float(d1) + __high2float(d1);
    float al = (g_a < cn) ? dot * 0.2041241452319315f : -INFINITY;

    float cm = al;
    cm = fmaxf(cm, __shfl_xor(cm, 4));
    cm = fmaxf(cm, __shfl_xor(cm, 8));
    cm = fmaxf(cm, __shfl_xor(cm, 16));
    cm = fmaxf(cm, __shfl_xor(cm, 32));
    float nm = fmaxf(m, cm);
    float r  = __expf(m - nm);          // first chunk: 0
    float e  = __expf(al - nm);         // padded lanes: 0
    float cs = e;
    cs += __shfl_xor(cs, 4);
    cs += __shfl_xor(cs, 8);
    cs += __shfl_xor(cs, 16);
    cs += __shfl_xor(cs, 32);
    s = s * r + cs;
    m = nm;

    float rv = __shfl(r, h_v);
    __half2 ch0 = __floats2half2_rn(0.f, 0.f), ch1 = ch0, ch2 = ch0;
    #pragma unroll
    for (int st = 0; st < 4; st++){
      int eidx = st * 4 + vg;
      float w = __shfl(e, 4 * min(eidx, cn - 1) + h_v);
      if (eidx >= cn) w = 0.f;
      __half2 w2 = __float2half2_rn(w);
      ch0 = __hfma2(w2, u2h2(vd[st][0]), ch0);
      ch1 = __hfma2(w2, u2h2(vd[st][1]), ch1);
      ch2 = __hfma2(w2, u2h2(vd[st][2]), ch2);
    }
    acc[0] = fmaf(acc[0], rv, __low2float(ch0));
    acc[1] = fmaf(acc[1], rv, __high2float(ch0));
    acc[2] = fmaf(acc[2], rv, __low2float(ch1));
    acc[3] = fmaf(acc[3], rv, __high2float(ch1));
    acc[4] = fmaf(acc[4], rv, __low2float(ch2));
    acc[5] = fmaf(acc[5], rv, __high2float(ch2));
  }

  #pragma unroll
  for (int i = 0; i < 6; i++){
    acc[i] += __shfl_xor(acc[i], 16);
    acc[i] += __shfl_xor(acc[i], 32);
  }
  float sv  = __shfl(s, h_v);
  float inv = (re > rs) ? 1.0f / sv : 0.f;
  float o[6], xr[6];
  #pragma unroll
  for (int i = 0; i < 6; i++) o[i] = acc[i] * inv;
  {
    const unsigned int* xp = (const unsigned int*)(qsc + (size_t)n * 384 + 192 + 12 * l_v);
    unsigned int x0 = xp[0], x1 = xp[1], x2 = xp[2];
    xr[0] = __low2float(u2h2(x0)); xr[1] = __high2float(u2h2(x0));
    xr[2] = __low2float(u2h2(x1)); xr[3] = __high2float(u2h2(x1));
    xr[4] = __low2float(u2h2(x2)); xr[5] = __high2float(u2h2(x2));
  }

  float p = 0.f;
  #pragma unroll
  for (int i = 0; i < 6; i++){
    int f = 6 * l_v + i;
    p = fmaf(o[i], wa[f], p);
    p = fmaf(xr[i], wc[f], p);
  }
  p += __shfl_xor(p, 1);
  p += __shfl_xor(p, 2);
  p += __shfl_xor(p, 4);
  p += __shfl_xor(p, 8);
  float g = 1.0f / (1.0f + __expf(-p));
  float y[6];
  #pragma unroll
  for (int i = 0; i < 6; i++) y[i] = fmaf(g, xr[i] - o[i], o[i]);

  if (mode == 0){
    #pragma unroll
    for (int i = 0; i < 6; i++)
      y[i] = 0.5f * y[i] * (1.0f + erff(y[i] * 0.7071067811865475f));
    if (vg == 0){
      short* op = h1b + (size_t)n * 96 + 6 * l_v;
      #pragma unroll
      for (int i = 0; i < 6; i++) op[i] = f2b(y[i]);
    }
  } else {
    float ssum = y[0] + y[1] + y[2] + y[3] + y[4] + y[5];
    ssum += __shfl_xor(ssum, 1);
    ssum += __shfl_xor(ssum, 2);
    ssum += __shfl_xor(ssum, 4);
    ssum += __shfl_xor(ssum, 8);
    float mu = ssum * (1.0f / 96.0f);
    float vsum = 0.f;
    #pragma unroll
    for (int i = 0; i < 6; i++){ float d = y[i] - mu; vsum += d * d; }
    vsum += __shfl_xor(vsum, 1);
    vsum += __shfl_xor(vsum, 2);
    vsum += __shfl_xor(vsum, 4);
    vsum += __shfl_xor(vsum, 8);
    float invs = rsqrtf(vsum * (1.0f / 96.0f) + 1e-5f);
    if (vg == 0){
      float* op = outp + (size_t)n * 96 + 6 * l_v;
      #pragma unroll
      for (int i = 0; i < 6; i++){
        int f = 6 * l_v + i;
        op[i] = (y[i] - mu) * invs * gamma[f] + beta[f];
      }
    }
  }
}

extern "C" void kernel_launch(void* const* d_in, const int* in_sizes, int n_in,
                              void* d_out, int out_size, void* d_ws, size_t ws_size,
                              hipStream_t stream){
  const float* x    = (const float*)d_in[0];
  const int*   ei   = (const int*)d_in[1];
  const float* Wq1  = (const float*)d_in[2];
  const float* bq1  = (const float*)d_in[3];
  const float* Wk1  = (const float*)d_in[4];
  const float* bk1  = (const float*)d_in[5];
  const float* Wv1  = (const float*)d_in[6];
  const float* bv1  = (const float*)d_in[7];
  const float* Ws1  = (const float*)d_in[8];
  const float* bs1  = (const float*)d_in[9];
  const float* Wb1  = (const float*)d_in[10];
  const float* Wq2  = (const float*)d_in[11];
  const float* bq2  = (const float*)d_in[12];
  const float* Wk2  = (const float*)d_in[13];
  const float* bk2  = (const float*)d_in[14];
  const float* Wv2  = (const float*)d_in[15];
  const float* bv2  = (const float*)d_in[16];
  const float* Ws2  = (const float*)d_in[17];
  const float* bs2  = (const float*)d_in[18];
  const float* Wb2  = (const float*)d_in[19];
  const float* gamma = (const float*)d_in[20];
  const float* beta  = (const float*)d_in[21];
  float* out = (float*)d_out;

  char* ws = (char*)d_ws;
  size_t off = 0;
  auto take = [&](size_t b) -> void* {
    void* p = ws + off;
    off += (b + 255) & ~(size_t)255;
    return p;
  };
  __half* qs           = (__half*)take((size_t)NN * 192 * 2);
  __half* kvb          = (__half*)take((size_t)NN * 192 * 2);
  short* h1b           = (short*)take((size_t)NN * 96 * 2);
  short* Wcat1         = (short*)take((size_t)384 * 128 * 2);
  short* Wcat2         = (short*)take((size_t)384 * 96 * 2);
  float* bcat1         = (float*)take(384 * 4);
  float* bcat2         = (float*)take(384 * 4);
  float* wa1           = (float*)take(96 * 4);
  float* wc1           = (float*)take(96 * 4);
  float* wa2           = (float*)take(96 * 4);
  float* wc2           = (float*)take(96 * 4);
  int* degC            = (int*)take((size_t)8 * NN * 4);
  int* epos            = (int*)take((size_t)EE * 4);
  int* base8           = (int*)take((size_t)NN * 8 * 4);
  int* row_ptr         = (int*)take((size_t)(NN + 1) * 4);
  unsigned short* col_src = (unsigned short*)take((size_t)EE * 2);
  int* psum            = (int*)take((size_t)SCAN_NB * 4);

  hipMemsetAsync(degC, 0, (size_t)8 * NN * 4, stream);
  // pack weights (tiny) -> enables gemm1
  pack_kernel<<<769, 128, 0, stream>>>(
      Wq1, bq1, Wk1, bk1, Wv1, bv1, Ws1, bs1,
      Wq2, bq2, Wk2, bk2, Wv2, bv2, Ws2, bs2,
      Wb1, Wb2, Wcat1, bcat1, Wcat2, bcat2, wa1, wc1, wa2, wc2);
  // hist || layer-1 gemm (independent work fused in one dispatch)
  histgemm_kernel<<<HISTB + GEMMB4, 256, 0, stream>>>(
      ei, degC, epos, x, Wcat1, bcat1, qs, kvb, NN);
  // CSR completion
  partial_sum_kernel<<<SCAN_NB, 256, 0, stream>>>(degC, psum);
  scan_partials_kernel<<<1, 256, 0, stream>>>(psum);
  final_scan_kernel<<<SCAN_NB, 256, 0, stream>>>(degC, psum, row_ptr, base8);
  fill_kernel<<<(EE + 255) / 256, 256, 0, stream>>>(ei, epos, base8, col_src);

  // layer 1 attention
  attn_kernel<<<(NN + 3) / 4, 256, 0, stream>>>(qs, kvb, row_ptr, col_src,
                                                wa1, wc1, nullptr, nullptr,
                                                nullptr, h1b, 0);
  // layer 2
  gemm_kernel<96, false><<<GEMMB4, 256, 0, stream>>>(h1b, Wcat2, bcat2, qs, kvb, NN);
  attn_kernel<<<(NN + 3) / 4, 256, 0, stream>>>(qs, kvb, row_ptr, col_src,
                                                wa2, wc2, gamma, beta,
                                                out, nullptr, 1);
}